// Round 8
// baseline (3004.778 us; speedup 1.0000x reference)
//
#include <hip/hip_runtime.h>

// Dims: B=16 C=32 N=400 T=12 R=64 G=16 E=64 H=2 DH=32 FE=256
#define TT 12

// ---------------------------------------------------------------------------
// Generic spatial contraction over (b,c) batches, vo-chunked via blockIdx.y.
// orientT=1 path register-tiled 4vo x 4t (round-7: old path was 2 loads per
// 2 FMA, latency-bound); per vi: 1 coalesced global float4 + 1 broadcast LDS
// b128 -> 16 FMA. Requires chunk%4==0 and TT==12 (all call sites satisfy).
// ---------------------------------------------------------------------------
__global__ void __launch_bounds__(256) k_spatial(
    const float* __restrict__ M, int orientT, int Vin, int Vout,
    const float* __restrict__ in, const float* __restrict__ base,
    float scale, int do_relu, float* __restrict__ out)
{
    __shared__ float in_lds[400 * TT];
    int bc = blockIdx.x;
    const float* ib = in + (size_t)bc * Vin * TT;
    for (int i = threadIdx.x; i < Vin * TT; i += 256) in_lds[i] = ib[i];
    __syncthreads();
    int chunk = Vout / gridDim.y;
    int vo0 = blockIdx.y * chunk;
    size_t obase = (size_t)bc * Vout * TT;
    if (orientT) {
        int ng = chunk >> 2;
        for (int idx = threadIdx.x; idx < ng * 3; idx += 256) {
            int vgi = idx / 3, tj = idx - (idx / 3) * 3;
            int vo = vo0 + vgi * 4;
            float a0x=0,a0y=0,a0z=0,a0w=0, a1x=0,a1y=0,a1z=0,a1w=0;
            float a2x=0,a2y=0,a2z=0,a2w=0, a3x=0,a3y=0,a3z=0,a3w=0;
            for (int vi = 0; vi < Vin; ++vi) {
                float4 m = *(const float4*)(M + (size_t)vi * Vout + vo);
                float4 xv = *(const float4*)(in_lds + vi * 12 + tj * 4);
                a0x += m.x*xv.x; a0y += m.x*xv.y; a0z += m.x*xv.z; a0w += m.x*xv.w;
                a1x += m.y*xv.x; a1y += m.y*xv.y; a1z += m.y*xv.z; a1w += m.y*xv.w;
                a2x += m.z*xv.x; a2y += m.z*xv.y; a2z += m.z*xv.z; a2w += m.z*xv.w;
                a3x += m.w*xv.x; a3y += m.w*xv.y; a3z += m.w*xv.z; a3w += m.w*xv.w;
            }
            float4 r[4];
            r[0] = make_float4(a0x,a0y,a0z,a0w);
            r[1] = make_float4(a1x,a1y,a1z,a1w);
            r[2] = make_float4(a2x,a2y,a2z,a2w);
            r[3] = make_float4(a3x,a3y,a3z,a3w);
            #pragma unroll
            for (int c = 0; c < 4; ++c) {
                float4 v = r[c];
                if (do_relu) {
                    v.x = fmaxf(v.x, 0.f); v.y = fmaxf(v.y, 0.f);
                    v.z = fmaxf(v.z, 0.f); v.w = fmaxf(v.w, 0.f);
                }
                v.x *= scale; v.y *= scale; v.z *= scale; v.w *= scale;
                size_t oi = obase + (size_t)(vo + c) * 12 + tj * 4;
                if (base) {
                    float4 bb = *(const float4*)(base + oi);
                    v.x += bb.x; v.y += bb.y; v.z += bb.z; v.w += bb.w;
                }
                *(float4*)(out + oi) = v;
            }
        }
    } else {
        for (int idx = threadIdx.x; idx < chunk * TT; idx += 256) {
            int vo = vo0 + idx / TT, t = idx - (idx / TT) * TT;
            float acc = 0.f;
            const float* Mr = M + (size_t)vo * Vin;
            for (int vi = 0; vi < Vin; ++vi)
                acc += Mr[vi] * in_lds[vi * TT + t];
            if (do_relu) acc = fmaxf(acc, 0.f);
            acc *= scale;
            size_t oi = obase + (size_t)vo * TT + t;
            if (base) acc += base[oi];
            out[oi] = acc;
        }
    }
}

// ---------------------------------------------------------------------------
// GCN combine v2: activations staged [c][s] (pad 100) so 4 consecutive s read
// as one broadcast b128; per c: 3 b128 + 3 b32 feed 12 FMA (was 6 b32/3 FMA).
// ---------------------------------------------------------------------------
__global__ void __launch_bounds__(256) k_gcn_combine(
    const float* __restrict__ x, const float* __restrict__ t0in,
    const float* __restrict__ t1in, const float* __restrict__ W,
    const float* __restrict__ bias, int V, float* __restrict__ out)
{
    __shared__ float xsc[32 * 100], t0c[32 * 100], t1c[32 * 100], WT[96 * 32];
    int nb = V / 8;
    int b = blockIdx.x / nb, n0 = (blockIdx.x % nb) * 8;
    for (int l = threadIdx.x; l < 3072; l += 256) {
        int c3 = l >> 5, o = l & 31;
        WT[l] = W[o * 96 + c3];
    }
    for (int l = threadIdx.x; l < 3072; l += 256) {
        int c = l / 96, s = l - c * 96;
        size_t g = (size_t)(b * 32 + c) * V * 12 + n0 * 12 + s;
        xsc[c * 100 + s] = x[g];
        t0c[c * 100 + s] = t0in[g];
        t1c[c * 100 + s] = t1in[g];
    }
    __syncthreads();
    int o = threadIdx.x & 31, slot = threadIdx.x >> 5;     // 8 slots
    for (int sg = slot; sg < 24; sg += 8) {
        float bz = bias[o];
        float c0 = bz, c1 = bz, c2 = bz, c3v = bz;
        for (int c = 0; c < 32; ++c) {
            float w0 = WT[c * 32 + o];
            float w1 = WT[(32 + c) * 32 + o];
            float w2 = WT[(64 + c) * 32 + o];
            float4 xv = *(const float4*)(xsc + c * 100 + 4 * sg);
            float4 y0 = *(const float4*)(t0c + c * 100 + 4 * sg);
            float4 y1 = *(const float4*)(t1c + c * 100 + 4 * sg);
            c0 += xv.x * w0 + y0.x * w1 + y1.x * w2;
            c1 += xv.y * w0 + y0.y * w1 + y1.y * w2;
            c2 += xv.z * w0 + y0.z * w1 + y1.z * w2;
            c3v += xv.w * w0 + y0.w * w1 + y1.w * w2;
        }
        size_t ob = ((size_t)(b * 32 + o) * V + n0) * 12 + 4 * sg;
        *(float4*)(out + ob) = make_float4(c0, c1, c2, c3v);
    }
}

// ---------------------------------------------------------------------------
// 1x1 conv C->E v2: x staged [c][s] pad-100; per c: 1 broadcast b128 + 1 b32
// feed 4 FMA (was 2 b32 / 1 FMA).
// ---------------------------------------------------------------------------
__global__ void __launch_bounds__(256) k_conv1(
    const float* __restrict__ x, const float* __restrict__ W,
    const float* __restrict__ bias, const float* __restrict__ dsadd,
    float* __restrict__ out)
{
    __shared__ float xsc[32 * 100];
    __shared__ float WT[2048];
    int b = blockIdx.x / 50, n0 = (blockIdx.x % 50) * 8;
    for (int l = threadIdx.x; l < 2048; l += 256) {
        int c = l >> 6, o = l & 63;
        WT[l] = W[o * 32 + c];
    }
    for (int l = threadIdx.x; l < 3072; l += 256) {
        int c = l / 96, s = l - c * 96;
        xsc[c * 100 + s] = x[(size_t)(b * 32 + c) * 4800 + n0 * 12 + s];
    }
    __syncthreads();
    int o = threadIdx.x & 63, slot = threadIdx.x >> 6;     // 4 slots
    for (int sg = slot; sg < 24; sg += 4) {
        float ad = bias[o];
        if (dsadd) ad += dsadd[(n0 + (4 * sg) / 12) * 64 + o];
        float c0 = ad, c1 = ad, c2 = ad, c3v = ad;
        for (int c = 0; c < 32; ++c) {
            float w = WT[(c << 6) + o];
            float4 xv = *(const float4*)(xsc + c * 100 + 4 * sg);
            c0 += xv.x * w; c1 += xv.y * w; c2 += xv.z * w; c3v += xv.w * w;
        }
        size_t ob = ((size_t)b * 4800 + n0 * 12 + 4 * sg) * 64 + o;
        out[ob] = c0;
        out[ob + 64] = c1;
        out[ob + 128] = c2;
        out[ob + 192] = c3v;
    }
}

// ---------------------------------------------------------------------------
// ds[n,e] = sum_m D_S[n,m] * W_embed[e,m] + b_embed[e]
// ---------------------------------------------------------------------------
__global__ void __launch_bounds__(64) k_ds(
    const float* __restrict__ D_S, const float* __restrict__ Wem,
    const float* __restrict__ bem, float* __restrict__ ds)
{
    __shared__ float row[400];
    int n = blockIdx.x;
    for (int i = threadIdx.x; i < 400; i += 64) row[i] = D_S[n * 400 + i];
    __syncthreads();
    int e = threadIdx.x;
    float acc = bem[e];
    const float* we = Wem + (size_t)e * 400;
    for (int m = 0; m < 400; ++m) acc += row[m] * we[m];
    ds[n * 64 + e] = acc;
}

// ---------------------------------------------------------------------------
// Ag partial (reference's mismatched reshape contraction)
// ---------------------------------------------------------------------------
__global__ void __launch_bounds__(256) k_agp(const float* __restrict__ xs,
                                             float* __restrict__ Ag)
{
    __shared__ float A[256 * 17], Bv[256 * 17];
    int i = blockIdx.x * 256 + threadIdx.x;  // < 6144
    int c1 = i / 192, b1 = (i / 12) & 15, t1 = i % 12;
    int t2 = i >> 9, b2 = (i >> 5) & 15, c2 = i & 31;
    for (int g = 0; g < 16; ++g) {
        A[threadIdx.x * 17 + g] = xs[((size_t)(b1 * 32 + c1) * 16 + g) * 12 + t1];
        Bv[threadIdx.x * 17 + g] = xs[((size_t)(b2 * 32 + c2) * 16 + g) * 12 + t2];
    }
    __syncthreads();
    int g1 = threadIdx.x >> 4, g2 = threadIdx.x & 15;
    float acc = 0.f;
    for (int k = 0; k < 256; ++k) acc += A[k * 17 + g1] * Bv[k * 17 + g2];
    atomicAdd(&Ag[threadIdx.x], acc);
}

// ---------------------------------------------------------------------------
// Ag -> relu(Ag-0.5) -> sg0/sg1 softmax(asym_adj)
// ---------------------------------------------------------------------------
__global__ void __launch_bounds__(64) k_agf(const float* __restrict__ Ag,
                                            float* __restrict__ sg0,
                                            float* __restrict__ sg1)
{
    __shared__ float Ar[256], rs[16], cs[16];
    int tid = threadIdx.x;
    for (int l = tid; l < 256; l += 64) Ar[l] = fmaxf(Ag[l] - 0.5f, 0.f);
    __syncthreads();
    if (tid < 16) {
        float r = 0.f, c = 0.f;
        for (int j = 0; j < 16; ++j) { r += Ar[tid * 16 + j]; c += Ar[j * 16 + tid]; }
        rs[tid] = (r > 0.f) ? 1.f / r : 0.f;
        cs[tid] = (c > 0.f) ? 1.f / c : 0.f;
    }
    __syncthreads();
    if (tid < 16) {
        float v[16], m, s;
        m = -1e30f;
        for (int j = 0; j < 16; ++j) { v[j] = Ar[tid * 16 + j] * rs[tid]; m = fmaxf(m, v[j]); }
        s = 0.f;
        for (int j = 0; j < 16; ++j) { v[j] = expf(v[j] - m); s += v[j]; }
        for (int j = 0; j < 16; ++j) sg0[tid * 16 + j] = v[j] / s;
        m = -1e30f;
        for (int j = 0; j < 16; ++j) { v[j] = Ar[j * 16 + tid] * cs[tid]; m = fmaxf(m, v[j]); }
        s = 0.f;
        for (int j = 0; j < 16; ++j) { v[j] = expf(v[j] - m); s += v[j]; }
        for (int j = 0; j < 16; ++j) sg1[tid * 16 + j] = v[j] / s;
    }
}

// ---------------------------------------------------------------------------
// QKV projection
// ---------------------------------------------------------------------------
__global__ void __launch_bounds__(256) k_qkv(
    const float* __restrict__ q, const float* __restrict__ Wq,
    const float* __restrict__ Wk, const float* __restrict__ Wv,
    float* __restrict__ qq, float* __restrict__ kk, float* __restrict__ vv)
{
    __shared__ float qs[64 * 33], wqT[1024], wkT[1024], wvT[1024];
    int g = blockIdx.x, n0 = blockIdx.y * 64;
    int b = g / 24, rem = g % 24, t = rem >> 1, h = rem & 1;
    int tid = threadIdx.x;
    for (int i = tid; i < 1024; i += 256) {
        int dd = i >> 5, e = i & 31;
        wqT[i] = Wq[e * 32 + dd];
        wkT[i] = Wk[e * 32 + dd];
        wvT[i] = Wv[e * 32 + dd];
    }
    for (int i = tid; i < 2048; i += 256) {
        int n = i >> 5, dd = i & 31;
        int gn = n0 + n;
        qs[n * 33 + dd] = (gn < 400)
            ? q[((size_t)b * 4800 + gn * 12 + t) * 64 + h * 32 + dd] : 0.f;
    }
    __syncthreads();
    int e = tid & 31, ng = tid >> 5;
    float aq[8], ak[8], av[8];
    #pragma unroll
    for (int k = 0; k < 8; ++k) { aq[k] = 0.f; ak[k] = 0.f; av[k] = 0.f; }
    for (int dd = 0; dd < 32; ++dd) {
        float wq = wqT[dd * 32 + e], wk = wkT[dd * 32 + e], wv = wvT[dd * 32 + e];
        #pragma unroll
        for (int k = 0; k < 8; ++k) {
            float xv = qs[(ng + 8 * k) * 33 + dd];
            aq[k] += xv * wq; ak[k] += xv * wk; av[k] += xv * wv;
        }
    }
    #pragma unroll
    for (int k = 0; k < 8; ++k) {
        int gn = n0 + ng + 8 * k;
        if (gn < 400) {
            size_t a = ((size_t)g * 400 + gn) * 32 + e;
            qq[a] = aq[k]; kk[a] = ak[k]; vv[a] = av[k];
        }
    }
}

// Softmax over one 7-slot energy row; writes p to PROW, sum into SVAR.
#define SMAX_ROW(EARR, PROW, SVAR) {                                          \
    if (l >= 16) EARR[6] = -1e30f;                                            \
    float m_ = EARR[0];                                                       \
    _Pragma("unroll") for (int j_ = 1; j_ < 7; ++j_) m_ = fmaxf(m_, EARR[j_]);\
    _Pragma("unroll") for (int o_ = 32; o_; o_ >>= 1)                         \
        m_ = fmaxf(m_, __shfl_xor(m_, o_));                                   \
    float ss_ = 0.f;                                                          \
    _Pragma("unroll") for (int j_ = 0; j_ < 7; ++j_) {                        \
        EARR[j_] = __expf((EARR[j_] - m_) * 0.125f); ss_ += EARR[j_]; }       \
    _Pragma("unroll") for (int o_ = 32; o_; o_ >>= 1)                         \
        ss_ += __shfl_xor(ss_, o_);                                           \
    SVAR = ss_;                                                               \
    _Pragma("unroll") for (int j_ = 0; j_ < 6; ++j_)                          \
        (PROW)[j_ * 64 + l] = EARR[j_];                                       \
    if (l < 16) (PROW)[384 + l] = EARR[6]; }

// ---------------------------------------------------------------------------
// Attention v4. 1024 thr (4 waves/SIMD). 4 q-rows per wave group: the 224
// kkT b32 reads per group now feed 896 FMA (4 FMA/read; v3 was 2). PV runs
// 2 rows at a time through the 800-float wave-private pbuf; V transposed to
// [32][402] read as float2 (2-way banks = free) halving V-read instructions.
// LDS: kkT 14368 + vvT 12864 + pbuf 12800 = 40032 fl = 160128 B.
// VGPR est ~90 (v3 measured 52); spill would reappear as GB-scale FETCH.
// ---------------------------------------------------------------------------
__global__ void __launch_bounds__(1024, 4) k_attn4(
    const float* __restrict__ qq, const float* __restrict__ kk,
    const float* __restrict__ vv, float* __restrict__ attnO)
{
    extern __shared__ float lds[];
    float* kkT = lds;             // 32*449
    float* vvT = kkT + 14368;     // 32*402
    float* pbuf = vvT + 12864;    // 16 waves * 800

    int g = blockIdx.x >> 1, rh = blockIdx.x & 1;
    const float* qq_g = qq + (size_t)g * 12800;
    const float* kk_g = kk + (size_t)g * 12800;
    const float* vv_g = vv + (size_t)g * 12800;
    int tid = threadIdx.x;

    for (int i = tid; i < 1568; i += 1024) {         // zero pad keys 400..448
        int d = i / 49, c = i - d * 49;
        kkT[d * 449 + 400 + c] = 0.f;
    }
    for (int i = tid; i < 12800; i += 1024) {
        int k = i >> 5, d = i & 31;
        kkT[d * 449 + k] = kk_g[i];
        vvT[d * 402 + k] = vv_g[i];
    }
    __syncthreads();

    int w = tid >> 6, l = tid & 63;                  // w in 0..15
    float* pw = pbuf + w * 800;
    int b = g / 24, rem = g % 24, t = rem >> 1, h = rem & 1;
    size_t obase = ((size_t)b * 4800 + t) * 64 + h * 32;
    int hh = l >> 5, d = l & 31;
    int kb0 = hh * 200;

    for (int r0 = rh * 200 + w * 4; r0 < rh * 200 + 200; r0 += 64) {
        float e0[7], e1[7], e2[7], e3[7];
        #pragma unroll
        for (int j = 0; j < 7; ++j) { e0[j]=0.f; e1[j]=0.f; e2[j]=0.f; e3[j]=0.f; }

        for (int db = 0; db < 4; ++db) {
            float q0[8], q1[8], q2[8], q3[8];
            #pragma unroll
            for (int dd = 0; dd < 8; ++dd) {
                q0[dd] = qq_g[(r0 + 0) * 32 + db * 8 + dd];
                q1[dd] = qq_g[(r0 + 1) * 32 + db * 8 + dd];
                q2[dd] = qq_g[(r0 + 2) * 32 + db * 8 + dd];
                q3[dd] = qq_g[(r0 + 3) * 32 + db * 8 + dd];
            }
            #pragma unroll
            for (int j = 0; j < 7; ++j) {
                #pragma unroll
                for (int dd = 0; dd < 8; ++dd) {
                    float kv = kkT[(db * 8 + dd) * 449 + j * 64 + l];
                    e0[j] += q0[dd] * kv;
                    e1[j] += q1[dd] * kv;
                    e2[j] += q2[dd] * kv;
                    e3[j] += q3[dd] * kv;
                }
            }
        }
        float s0v, s1v, s2v, s3v;
        // ---- rows 0,1 ----
        SMAX_ROW(e0, pw, s0v);
        SMAX_ROW(e1, pw + 400, s1v);
        asm volatile("" ::: "memory");
        {
            float o0 = 0.f, o1 = 0.f;
            const float* pr0 = pw + hh * 200;
            const float* pr1 = pw + 400 + hh * 200;
            const float* vr = vvT + d * 402 + kb0;
            for (int kb = 0; kb < 200; kb += 4) {
                float4 p0 = *(const float4*)(pr0 + kb);
                float4 p1 = *(const float4*)(pr1 + kb);
                float2 va = *(const float2*)(vr + kb);
                float2 vb = *(const float2*)(vr + kb + 2);
                o0 += p0.x * va.x + p0.y * va.y + p0.z * vb.x + p0.w * vb.y;
                o1 += p1.x * va.x + p1.y * va.y + p1.z * vb.x + p1.w * vb.y;
            }
            asm volatile("" ::: "memory");
            o0 += __shfl_down(o0, 32);
            o1 += __shfl_down(o1, 32);
            if (l < 32) {
                attnO[obase + (size_t)(r0 + 0) * 768 + d] = o0 / s0v;
                attnO[obase + (size_t)(r0 + 1) * 768 + d] = o1 / s1v;
            }
        }
        asm volatile("" ::: "memory");
        // ---- rows 2,3 (pbuf reuse; wave-private, in-order DS pipe) ----
        SMAX_ROW(e2, pw, s2v);
        SMAX_ROW(e3, pw + 400, s3v);
        asm volatile("" ::: "memory");
        {
            float o2 = 0.f, o3 = 0.f;
            const float* pr0 = pw + hh * 200;
            const float* pr1 = pw + 400 + hh * 200;
            const float* vr = vvT + d * 402 + kb0;
            for (int kb = 0; kb < 200; kb += 4) {
                float4 p0 = *(const float4*)(pr0 + kb);
                float4 p1 = *(const float4*)(pr1 + kb);
                float2 va = *(const float2*)(vr + kb);
                float2 vb = *(const float2*)(vr + kb + 2);
                o2 += p0.x * va.x + p0.y * va.y + p0.z * vb.x + p0.w * vb.y;
                o3 += p1.x * va.x + p1.y * va.y + p1.z * vb.x + p1.w * vb.y;
            }
            asm volatile("" ::: "memory");
            o2 += __shfl_down(o2, 32);
            o3 += __shfl_down(o3, 32);
            if (l < 32) {
                attnO[obase + (size_t)(r0 + 2) * 768 + d] = o2 / s2v;
                attnO[obase + (size_t)(r0 + 3) * 768 + d] = o3 / s3v;
            }
        }
        asm volatile("" ::: "memory");
    }
}

// ---------------------------------------------------------------------------
// A1 v2 (verified round 7): x = LN(attnO @ Wfc^T + bfc + q), 4x4 reg tile.
// ---------------------------------------------------------------------------
__global__ void __launch_bounds__(256) k_A1n(
    const float* __restrict__ attnO, const float* __restrict__ Wfc,
    const float* __restrict__ bfc, const float* __restrict__ qbuf,
    const float* __restrict__ w1, const float* __restrict__ b1,
    float* __restrict__ xout)
{
    __shared__ float WT[64 * 65], ao[64 * 65], qs[64 * 65];
    size_t R0 = (size_t)blockIdx.x * 64;
    int tid = threadIdx.x;
    for (int l = tid; l < 4096; l += 256) {
        int o = l >> 6, e = l & 63;
        WT[e * 65 + o] = Wfc[l];
    }
    for (int i = tid; i < 1024; i += 256) {
        int r = i >> 4, c4 = (i & 15) * 4;
        *(float4*)(ao + r * 65 + c4) = *(const float4*)(attnO + (R0 + r) * 64 + c4);
        *(float4*)(qs + r * 65 + c4) = *(const float4*)(qbuf + (R0 + r) * 64 + c4);
    }
    __syncthreads();

    int oj = tid & 15, ri = tid >> 4;
    float acc[4][4];
    #pragma unroll
    for (int rr = 0; rr < 4; ++rr)
        #pragma unroll
        for (int cc = 0; cc < 4; ++cc) acc[rr][cc] = 0.f;

    for (int eb = 0; eb < 16; ++eb) {
        float w[4][4], u[4][4];
        #pragma unroll
        for (int k = 0; k < 4; ++k) {
            float4 t = *(const float4*)(WT + (eb * 4 + k) * 65 + 4 * oj);
            w[k][0] = t.x; w[k][1] = t.y; w[k][2] = t.z; w[k][3] = t.w;
        }
        #pragma unroll
        for (int rr = 0; rr < 4; ++rr) {
            float4 t = *(const float4*)(ao + (4 * ri + rr) * 65 + eb * 4);
            u[rr][0] = t.x; u[rr][1] = t.y; u[rr][2] = t.z; u[rr][3] = t.w;
        }
        #pragma unroll
        for (int rr = 0; rr < 4; ++rr)
            #pragma unroll
            for (int k = 0; k < 4; ++k) {
                float uv = u[rr][k];
                acc[rr][0] += uv * w[k][0];
                acc[rr][1] += uv * w[k][1];
                acc[rr][2] += uv * w[k][2];
                acc[rr][3] += uv * w[k][3];
            }
    }
    float bf[4];
    #pragma unroll
    for (int cc = 0; cc < 4; ++cc) bf[cc] = bfc[4 * oj + cc];
    #pragma unroll
    for (int rr = 0; rr < 4; ++rr)
        #pragma unroll
        for (int cc = 0; cc < 4; ++cc) {
            int r = 4 * ri + rr, o = 4 * oj + cc;
            qs[r * 65 + o] += acc[rr][cc] + bf[cc];
        }
    __syncthreads();
    int r = tid >> 2, sb = tid & 3;
    float vals[16];
    float sm = 0.f;
    #pragma unroll
    for (int i = 0; i < 4; ++i) {
        float4 t = *(const float4*)(qs + r * 65 + sb * 16 + 4 * i);
        vals[4 * i + 0] = t.x; vals[4 * i + 1] = t.y;
        vals[4 * i + 2] = t.z; vals[4 * i + 3] = t.w;
        sm += t.x + t.y + t.z + t.w;
    }
    sm += __shfl_xor(sm, 1); sm += __shfl_xor(sm, 2);
    float mean = sm * (1.f / 64.f);
    float vs = 0.f;
    #pragma unroll
    for (int i = 0; i < 16; ++i) { float dv = vals[i] - mean; vs += dv * dv; }
    vs += __shfl_xor(vs, 1); vs += __shfl_xor(vs, 2);
    float inv = rsqrtf(vs * (1.f / 64.f) + 1e-5f);
    #pragma unroll
    for (int i = 0; i < 16; ++i) {
        int o = sb * 16 + i;
        xout[(R0 + r) * 64 + o] = (vals[i] - mean) * inv * w1[o] + b1[o];
    }
}

// ---------------------------------------------------------------------------
// A2 fused FF (unchanged)
// ---------------------------------------------------------------------------
__global__ void __launch_bounds__(512, 2) k_A2n(
    const float* __restrict__ xin, const float* __restrict__ Wff1,
    const float* __restrict__ bff1, const float* __restrict__ Wff2,
    const float* __restrict__ bff2, const float* __restrict__ w2,
    const float* __restrict__ b2, float* __restrict__ US)
{
    extern __shared__ float lds[];
    float* xs = lds;             // 64*65 = 4160
    float* Wb = xs + 4160;       // 16384
    float* fhT = Wb + 16384;     // 256*65 = 16640
    size_t R0 = (size_t)blockIdx.x * 64;
    int tid = threadIdx.x;
    for (int i = tid; i < 4096; i += 512) {
        int r = i >> 6, e = i & 63;
        xs[r * 65 + e] = xin[(R0 + r) * 64 + e];
    }
    for (int i = tid; i < 16384; i += 512) {
        int e = i >> 8, f = i & 255;
        Wb[i] = Wff1[f * 64 + e];
    }
    __syncthreads();
    int l = tid & 63, g = tid >> 6;
    {
        float acc[4][8];
        #pragma unroll
        for (int j = 0; j < 4; ++j)
            #pragma unroll
            for (int ri = 0; ri < 8; ++ri) acc[j][ri] = 0.f;
        for (int e = 0; e < 64; ++e) {
            float xr[8];
            #pragma unroll
            for (int ri = 0; ri < 8; ++ri) xr[ri] = xs[(g * 8 + ri) * 65 + e];
            #pragma unroll
            for (int j = 0; j < 4; ++j) {
                float wv = Wb[e * 256 + l + 64 * j];
                #pragma unroll
                for (int ri = 0; ri < 8; ++ri) acc[j][ri] += xr[ri] * wv;
            }
        }
        #pragma unroll
        for (int j = 0; j < 4; ++j) {
            float bb = bff1[l + 64 * j];
            #pragma unroll
            for (int ri = 0; ri < 8; ++ri)
                fhT[(l + 64 * j) * 65 + g * 8 + ri] = fmaxf(acc[j][ri] + bb, 0.f);
        }
    }
    __syncthreads();
    for (int i = tid; i < 16384; i += 512) {
        int f = i >> 6, o = i & 63;
        Wb[i] = Wff2[o * 256 + f];
    }
    __syncthreads();
    float acc2[8];
    #pragma unroll
    for (int oi = 0; oi < 8; ++oi) acc2[oi] = 0.f;
    for (int f = 0; f < 256; ++f) {
        float fv = fhT[f * 65 + l];
        float4 wa = *(const float4*)(Wb + f * 64 + g * 8);
        float4 wb_ = *(const float4*)(Wb + f * 64 + g * 8 + 4);
        acc2[0] += fv * wa.x;  acc2[1] += fv * wa.y;
        acc2[2] += fv * wa.z;  acc2[3] += fv * wa.w;
        acc2[4] += fv * wb_.x; acc2[5] += fv * wb_.y;
        acc2[6] += fv * wb_.z; acc2[7] += fv * wb_.w;
    }
    __syncthreads();
    float* lnb = Wb;
    float* mM = Wb + 4160;
    float* mI = Wb + 4224;
    #pragma unroll
    for (int oi = 0; oi < 8; ++oi) {
        int o = g * 8 + oi;
        lnb[l * 65 + o] = acc2[oi] + bff2[o] + xs[l * 65 + o];
    }
    __syncthreads();
    int r = tid >> 3, sb = tid & 7;
    float v[8];
    float sm = 0.f;
    #pragma unroll
    for (int i = 0; i < 8; ++i) { v[i] = lnb[r * 65 + sb + 8 * i]; sm += v[i]; }
    sm += __shfl_xor(sm, 1); sm += __shfl_xor(sm, 2); sm += __shfl_xor(sm, 4);
    float mean = sm * (1.f / 64.f);
    float vs = 0.f;
    #pragma unroll
    for (int i = 0; i < 8; ++i) { float dv = v[i] - mean; vs += dv * dv; }
    vs += __shfl_xor(vs, 1); vs += __shfl_xor(vs, 2); vs += __shfl_xor(vs, 4);
    float inv = rsqrtf(vs * (1.f / 64.f) + 1e-5f);
    if (sb == 0) { mM[r] = mean; mI[r] = inv; }
    __syncthreads();
    for (int i = tid; i < 4096; i += 512) {
        int rr = i >> 6, o = i & 63;
        US[(R0 + rr) * 64 + o] = (lnb[rr * 65 + o] - mM[rr]) * mI[rr] * w2[o] + b2[o];
    }
}

// ---------------------------------------------------------------------------
// A3 v2 (verified round 7): gate + blend + final conv, 4x4 reg tile.
// ---------------------------------------------------------------------------
__global__ void __launch_bounds__(256) k_A3n(
    const float* __restrict__ US, const float* __restrict__ Xc,
    const float* __restrict__ Wfs, const float* __restrict__ bfs,
    const float* __restrict__ Wfg, const float* __restrict__ bfg,
    const float* __restrict__ Wc11, const float* __restrict__ bc11,
    float* __restrict__ out)
{
    extern __shared__ float lds[];
    float* WsT = lds;
    float* WgT = WsT + 4160;
    float* WcT = WgT + 4160;
    float* us  = WcT + 2112;
    float* xc  = us + 4160;
    size_t R0 = (size_t)blockIdx.x * 64;
    int tid = threadIdx.x;
    for (int l = tid; l < 4096; l += 256) {
        int o = l >> 6, e = l & 63;
        WsT[e * 65 + o] = Wfs[l];
        WgT[e * 65 + o] = Wfg[l];
    }
    for (int l = tid; l < 2048; l += 256) {
        int oc = l >> 6, e = l & 63;
        WcT[e * 33 + oc] = Wc11[l];
    }
    for (int i = tid; i < 1024; i += 256) {
        int r = i >> 4, c4 = (i & 15) * 4;
        *(float4*)(us + r * 65 + c4) = *(const float4*)(US + (R0 + r) * 64 + c4);
        *(float4*)(xc + r * 65 + c4) = *(const float4*)(Xc + (R0 + r) * 64 + c4);
    }
    __syncthreads();

    int oj = tid & 15, ri = tid >> 4;
    float a1[4][4], a2[4][4];
    #pragma unroll
    for (int rr = 0; rr < 4; ++rr)
        #pragma unroll
        for (int cc = 0; cc < 4; ++cc) { a1[rr][cc] = 0.f; a2[rr][cc] = 0.f; }

    for (int eb = 0; eb < 16; ++eb) {
        {
            float w[4][4], u[4][4];
            #pragma unroll
            for (int k = 0; k < 4; ++k) {
                float4 t = *(const float4*)(WsT + (eb * 4 + k) * 65 + 4 * oj);
                w[k][0] = t.x; w[k][1] = t.y; w[k][2] = t.z; w[k][3] = t.w;
            }
            #pragma unroll
            for (int rr = 0; rr < 4; ++rr) {
                float4 t = *(const float4*)(us + (4 * ri + rr) * 65 + eb * 4);
                u[rr][0] = t.x; u[rr][1] = t.y; u[rr][2] = t.z; u[rr][3] = t.w;
            }
            #pragma unroll
            for (int rr = 0; rr < 4; ++rr)
                #pragma unroll
                for (int k = 0; k < 4; ++k) {
                    float uv = u[rr][k];
                    a1[rr][0] += uv * w[k][0];
                    a1[rr][1] += uv * w[k][1];
                    a1[rr][2] += uv * w[k][2];
                    a1[rr][3] += uv * w[k][3];
                }
        }
        {
            float w[4][4], u[4][4];
            #pragma unroll
            for (int k = 0; k < 4; ++k) {
                float4 t = *(const float4*)(WgT + (eb * 4 + k) * 65 + 4 * oj);
                w[k][0] = t.x; w[k][1] = t.y; w[k][2] = t.z; w[k][3] = t.w;
            }
            #pragma unroll
            for (int rr = 0; rr < 4; ++rr) {
                float4 t = *(const float4*)(xc + (4 * ri + rr) * 65 + eb * 4);
                u[rr][0] = t.x; u[rr][1] = t.y; u[rr][2] = t.z; u[rr][3] = t.w;
            }
            #pragma unroll
            for (int rr = 0; rr < 4; ++rr)
                #pragma unroll
                for (int k = 0; k < 4; ++k) {
                    float uv = u[rr][k];
                    a2[rr][0] += uv * w[k][0];
                    a2[rr][1] += uv * w[k][1];
                    a2[rr][2] += uv * w[k][2];
                    a2[rr][3] += uv * w[k][3];
                }
        }
    }
    __syncthreads();
    float bs[4], bg2[4];
    #pragma unroll
    for (int cc = 0; cc < 4; ++cc) { bs[cc] = bfs[4 * oj + cc]; bg2[cc] = bfg[4 * oj + cc]; }
    #pragma unroll
    for (int rr = 0; rr < 4; ++rr)
        #pragma unroll
        for (int cc = 0; cc < 4; ++cc) {
            int r = 4 * ri + rr, o = 4 * oj + cc;
            float gg = 1.f / (1.f + __expf(-(a1[rr][cc] + bs[cc] + a2[rr][cc] + bg2[cc])));
            float uv = us[r * 65 + o], xv = xc[r * 65 + o];
            us[r * 65 + o] = gg * uv + (1.f - gg) * xv;
        }
    __syncthreads();

    int ocj = tid & 7, rg = tid >> 3;
    float c2[2][4];
    #pragma unroll
    for (int rr = 0; rr < 2; ++rr)
        #pragma unroll
        for (int cc = 0; cc < 4; ++cc) c2[rr][cc] = bc11[4 * ocj + cc];
    for (int eb = 0; eb < 16; ++eb) {
        float w[4][4], p[2][4];
        #pragma unroll
        for (int k = 0; k < 4; ++k) {
            float4 t = *(const float4*)(WcT + (eb * 4 + k) * 33 + 4 * ocj);
            w[k][0] = t.x; w[k][1] = t.y; w[k][2] = t.z; w[k][3] = t.w;
        }
        #pragma unroll
        for (int rr = 0; rr < 2; ++rr) {
            float4 t = *(const float4*)(us + (2 * rg + rr) * 65 + eb * 4);
            p[rr][0] = t.x; p[rr][1] = t.y; p[rr][2] = t.z; p[rr][3] = t.w;
        }
        #pragma unroll
        for (int rr = 0; rr < 2; ++rr)
            #pragma unroll
            for (int k = 0; k < 4; ++k) {
                float pv = p[rr][k];
                c2[rr][0] += pv * w[k][0];
                c2[rr][1] += pv * w[k][1];
                c2[rr][2] += pv * w[k][2];
                c2[rr][3] += pv * w[k][3];
            }
    }
    int b = (int)(R0 / 4800);
    int rr0 = (int)(R0 % 4800);
    #pragma unroll
    for (int cc = 0; cc < 4; ++cc)
        #pragma unroll
        for (int rr = 0; rr < 2; ++rr)
            out[(size_t)(b * 32 + 4 * ocj + cc) * 4800 + rr0 + 2 * rg + rr] = c2[rr][cc];
}

// ---------------------------------------------------------------------------
extern "C" void kernel_launch(void* const* d_in, const int* in_sizes, int n_in,
                              void* d_out, int out_size, void* d_ws, size_t ws_size,
                              hipStream_t stream)
{
    (void)in_sizes; (void)n_in; (void)out_size; (void)ws_size;
    const float* query = (const float*)d_in[2];
    const float* s0    = (const float*)d_in[3];
    const float* s1    = (const float*)d_in[4];
    const float* sr0   = (const float*)d_in[5];
    const float* sr1   = (const float*)d_in[6];
    const float* Mrg   = (const float*)d_in[7];
    const float* Mor   = (const float*)d_in[8];
    const float* D_S   = (const float*)d_in[9];
    const float* Wc1   = (const float*)d_in[10];
    const float* bc1   = (const float*)d_in[11];
    const float* Wc11  = (const float*)d_in[12];
    const float* bc11  = (const float*)d_in[13];
    const float* Wg    = (const float*)d_in[14];
    const float* bg    = (const float*)d_in[15];
    const float* Wem   = (const float*)d_in[16];
    const float* bem   = (const float*)d_in[17];
    const float* Wq    = (const float*)d_in[18];
    const float* Wk    = (const float*)d_in[19];
    const float* Wv    = (const float*)d_in[20];
    const float* Wfc   = (const float*)d_in[21];
    const float* bfc   = (const float*)d_in[22];
    const float* ln1w  = (const float*)d_in[23];
    const float* ln1b  = (const float*)d_in[24];
    const float* ln2w  = (const float*)d_in[25];
    const float* ln2b  = (const float*)d_in[26];
    const float* Wff1  = (const float*)d_in[27];
    const float* bff1  = (const float*)d_in[28];
    const float* Wff2  = (const float*)d_in[29];
    const float* bff2  = (const float*)d_in[30];
    const float* Wfs   = (const float*)d_in[31];
    const float* bfs   = (const float*)d_in[32];
    const float* Wfg   = (const float*)d_in[33];
    const float* bfg   = (const float*)d_in[34];

    float* ws = (float*)d_ws;
    size_t off = 0;
    auto alloc = [&](size_t n) { float* p = ws + off; off += n; return p; };
    float* q_buf = alloc(4915200);   // (B,N,T,E)
    float* Xc    = alloc(4915200);   // doubles as qq pre-CHGCN
    float* x_buf = alloc(4915200);   // doubles as attnO (in-place A1)
    float* US    = alloc(4915200);   // doubles as vv pre-A2
    float* ho    = alloc(2457600);   // (B,C,N,T)
    float* t0    = alloc(2457600);
    float* t1    = alloc(2457600);   // t0+t1 contiguous: doubles as kk
    float* xr    = alloc(393216);    // (B,C,R,T)
    float* tr0   = alloc(393216);
    float* tr1   = alloc(393216);
    float* hr    = alloc(393216);
    float* xsg   = alloc(98304);     // (B,C,G,T)
    float* tg0   = alloc(98304);
    float* tg1   = alloc(98304);
    float* xg0   = alloc(98304);
    float* dsb   = alloc(25600);     // (N,E)
    float* Ag    = alloc(256);
    float* sg0   = alloc(256);
    float* sg1   = alloc(256);

    float* qq    = Xc;               // live only during [k_qkv, k_attn4]
    float* kk    = t0;
    float* vv    = US;
    float* attnO = x_buf;

    float* out_main = (float*)d_out;          // (B,C,N,T)
    float* out_xc   = out_main + 2457600;     // (B,C,R,T) final hr
    float* out_xs   = out_main + 2850816;     // (B,C,G,T) final xg

    hipFuncSetAttribute((const void*)k_attn4,
                        hipFuncAttributeMaxDynamicSharedMemorySize, 160128);
    hipFuncSetAttribute((const void*)k_A2n,
                        hipFuncAttributeMaxDynamicSharedMemorySize, 148736);
    hipFuncSetAttribute((const void*)k_A3n,
                        hipFuncAttributeMaxDynamicSharedMemorySize, 75008);

    hipMemsetAsync(Ag, 0, 256 * sizeof(float), stream);

    // ---- Transformer front ----
    k_ds<<<400, 64, 0, stream>>>(D_S, Wem, bem, dsb);
    k_conv1<<<800, 256, 0, stream>>>(query, Wc1, bc1, dsb, q_buf);
    k_qkv<<<dim3(384, 7), 256, 0, stream>>>(q_buf, Wq, Wk, Wv, qq, kk, vv);
    k_attn4<<<768, 1024, 160128, stream>>>(qq, kk, vv, attnO);
    k_A1n<<<1200, 256, 0, stream>>>(attnO, Wfc, bfc, q_buf, ln1w, ln1b, x_buf);
    k_A2n<<<1200, 512, 148736, stream>>>(x_buf, Wff1, bff1, Wff2, bff2,
                                         ln2w, ln2b, US);

    // ---- CHGCN ----
    k_spatial<<<dim3(512, 4), 256, 0, stream>>>(s0, 1, 400, 400, query, nullptr, 1.f, 0, t0);
    k_spatial<<<dim3(512, 4), 256, 0, stream>>>(s1, 1, 400, 400, query, nullptr, 1.f, 0, t1);
    k_gcn_combine<<<800, 256, 0, stream>>>(query, t0, t1, Wg, bg, 400, ho);
    k_spatial<<<dim3(512, 1), 256, 0, stream>>>(Mor, 1, 400, 64, query, nullptr, 1.f, 0, xr);
    k_spatial<<<dim3(512, 1), 256, 0, stream>>>(sr0, 1, 64, 64, xr, nullptr, 1.f, 0, tr0);
    k_spatial<<<dim3(512, 1), 256, 0, stream>>>(sr1, 1, 64, 64, xr, nullptr, 1.f, 0, tr1);
    k_gcn_combine<<<128, 256, 0, stream>>>(xr, tr0, tr1, Wg, bg, 64, hr);
    k_spatial<<<dim3(512, 1), 256, 0, stream>>>(Mrg, 1, 64, 16, xr, nullptr, 1.f, 0, xsg);
    k_agp<<<24, 256, 0, stream>>>(xsg, Ag);
    k_agf<<<1, 64, 0, stream>>>(Ag, sg0, sg1);
    k_spatial<<<dim3(512, 1), 256, 0, stream>>>(sg0, 1, 16, 16, xsg, nullptr, 1.f, 0, tg0);
    k_spatial<<<dim3(512, 1), 256, 0, stream>>>(sg1, 1, 16, 16, xsg, nullptr, 1.f, 0, tg1);
    k_gcn_combine<<<32, 256, 0, stream>>>(xsg, tg0, tg1, Wg, bg, 16, xg0);
    k_spatial<<<dim3(512, 1), 256, 0, stream>>>(Mrg, 0, 16, 64, xg0, hr, 0.5f, 1, hr);
    k_spatial<<<dim3(512, 4), 256, 0, stream>>>(Mor, 0, 64, 400, hr, ho, 0.5f, 1, ho);
    k_spatial<<<dim3(512, 1), 256, 0, stream>>>(Mor, 1, 400, 64, ho, hr, 0.5f, 1, out_xc);
    k_spatial<<<dim3(512, 1), 256, 0, stream>>>(Mrg, 1, 64, 16, out_xc, xg0, 0.5f, 1, out_xs);

    // ---- Tail ----
    k_conv1<<<800, 256, 0, stream>>>(ho, Wc1, bc1, nullptr, Xc);
    k_A3n<<<1200, 256, 75008, stream>>>(US, Xc, Wfs, bfs, Wfg, bfg, Wc11, bc11, out_main);
}

// Round 9
// 2127.042 us; speedup vs baseline: 1.4127x; 1.4127x over previous
//
#include <hip/hip_runtime.h>

// Dims: B=16 C=32 N=400 T=12 R=64 G=16 E=64 H=2 DH=32 FE=256
#define TT 12

// ---------------------------------------------------------------------------
// Generic spatial contraction over (b,c) batches, vo-chunked via blockIdx.y.
// orientT=1 path register-tiled 4vo x 4t (verified round 8).
// ---------------------------------------------------------------------------
__global__ void __launch_bounds__(256) k_spatial(
    const float* __restrict__ M, int orientT, int Vin, int Vout,
    const float* __restrict__ in, const float* __restrict__ base,
    float scale, int do_relu, float* __restrict__ out)
{
    __shared__ float in_lds[400 * TT];
    int bc = blockIdx.x;
    const float* ib = in + (size_t)bc * Vin * TT;
    for (int i = threadIdx.x; i < Vin * TT; i += 256) in_lds[i] = ib[i];
    __syncthreads();
    int chunk = Vout / gridDim.y;
    int vo0 = blockIdx.y * chunk;
    size_t obase = (size_t)bc * Vout * TT;
    if (orientT) {
        int ng = chunk >> 2;
        for (int idx = threadIdx.x; idx < ng * 3; idx += 256) {
            int vgi = idx / 3, tj = idx - (idx / 3) * 3;
            int vo = vo0 + vgi * 4;
            float a0x=0,a0y=0,a0z=0,a0w=0, a1x=0,a1y=0,a1z=0,a1w=0;
            float a2x=0,a2y=0,a2z=0,a2w=0, a3x=0,a3y=0,a3z=0,a3w=0;
            for (int vi = 0; vi < Vin; ++vi) {
                float4 m = *(const float4*)(M + (size_t)vi * Vout + vo);
                float4 xv = *(const float4*)(in_lds + vi * 12 + tj * 4);
                a0x += m.x*xv.x; a0y += m.x*xv.y; a0z += m.x*xv.z; a0w += m.x*xv.w;
                a1x += m.y*xv.x; a1y += m.y*xv.y; a1z += m.y*xv.z; a1w += m.y*xv.w;
                a2x += m.z*xv.x; a2y += m.z*xv.y; a2z += m.z*xv.z; a2w += m.z*xv.w;
                a3x += m.w*xv.x; a3y += m.w*xv.y; a3z += m.w*xv.z; a3w += m.w*xv.w;
            }
            float4 r[4];
            r[0] = make_float4(a0x,a0y,a0z,a0w);
            r[1] = make_float4(a1x,a1y,a1z,a1w);
            r[2] = make_float4(a2x,a2y,a2z,a2w);
            r[3] = make_float4(a3x,a3y,a3z,a3w);
            #pragma unroll
            for (int c = 0; c < 4; ++c) {
                float4 v = r[c];
                if (do_relu) {
                    v.x = fmaxf(v.x, 0.f); v.y = fmaxf(v.y, 0.f);
                    v.z = fmaxf(v.z, 0.f); v.w = fmaxf(v.w, 0.f);
                }
                v.x *= scale; v.y *= scale; v.z *= scale; v.w *= scale;
                size_t oi = obase + (size_t)(vo + c) * 12 + tj * 4;
                if (base) {
                    float4 bb = *(const float4*)(base + oi);
                    v.x += bb.x; v.y += bb.y; v.z += bb.z; v.w += bb.w;
                }
                *(float4*)(out + oi) = v;
            }
        }
    } else {
        for (int idx = threadIdx.x; idx < chunk * TT; idx += 256) {
            int vo = vo0 + idx / TT, t = idx - (idx / TT) * TT;
            float acc = 0.f;
            const float* Mr = M + (size_t)vo * Vin;
            for (int vi = 0; vi < Vin; ++vi)
                acc += Mr[vi] * in_lds[vi * TT + t];
            if (do_relu) acc = fmaxf(acc, 0.f);
            acc *= scale;
            size_t oi = obase + (size_t)vo * TT + t;
            if (base) acc += base[oi];
            out[oi] = acc;
        }
    }
}

// ---------------------------------------------------------------------------
// GCN combine v2 (verified round 8)
// ---------------------------------------------------------------------------
__global__ void __launch_bounds__(256) k_gcn_combine(
    const float* __restrict__ x, const float* __restrict__ t0in,
    const float* __restrict__ t1in, const float* __restrict__ W,
    const float* __restrict__ bias, int V, float* __restrict__ out)
{
    __shared__ float xsc[32 * 100], t0c[32 * 100], t1c[32 * 100], WT[96 * 32];
    int nb = V / 8;
    int b = blockIdx.x / nb, n0 = (blockIdx.x % nb) * 8;
    for (int l = threadIdx.x; l < 3072; l += 256) {
        int c3 = l >> 5, o = l & 31;
        WT[l] = W[o * 96 + c3];
    }
    for (int l = threadIdx.x; l < 3072; l += 256) {
        int c = l / 96, s = l - c * 96;
        size_t g = (size_t)(b * 32 + c) * V * 12 + n0 * 12 + s;
        xsc[c * 100 + s] = x[g];
        t0c[c * 100 + s] = t0in[g];
        t1c[c * 100 + s] = t1in[g];
    }
    __syncthreads();
    int o = threadIdx.x & 31, slot = threadIdx.x >> 5;     // 8 slots
    for (int sg = slot; sg < 24; sg += 8) {
        float bz = bias[o];
        float c0 = bz, c1 = bz, c2 = bz, c3v = bz;
        for (int c = 0; c < 32; ++c) {
            float w0 = WT[c * 32 + o];
            float w1 = WT[(32 + c) * 32 + o];
            float w2 = WT[(64 + c) * 32 + o];
            float4 xv = *(const float4*)(xsc + c * 100 + 4 * sg);
            float4 y0 = *(const float4*)(t0c + c * 100 + 4 * sg);
            float4 y1 = *(const float4*)(t1c + c * 100 + 4 * sg);
            c0 += xv.x * w0 + y0.x * w1 + y1.x * w2;
            c1 += xv.y * w0 + y0.y * w1 + y1.y * w2;
            c2 += xv.z * w0 + y0.z * w1 + y1.z * w2;
            c3v += xv.w * w0 + y0.w * w1 + y1.w * w2;
        }
        size_t ob = ((size_t)(b * 32 + o) * V + n0) * 12 + 4 * sg;
        *(float4*)(out + ob) = make_float4(c0, c1, c2, c3v);
    }
}

// ---------------------------------------------------------------------------
// 1x1 conv C->E v2 (verified round 8)
// ---------------------------------------------------------------------------
__global__ void __launch_bounds__(256) k_conv1(
    const float* __restrict__ x, const float* __restrict__ W,
    const float* __restrict__ bias, const float* __restrict__ dsadd,
    float* __restrict__ out)
{
    __shared__ float xsc[32 * 100];
    __shared__ float WT[2048];
    int b = blockIdx.x / 50, n0 = (blockIdx.x % 50) * 8;
    for (int l = threadIdx.x; l < 2048; l += 256) {
        int c = l >> 6, o = l & 63;
        WT[l] = W[o * 32 + c];
    }
    for (int l = threadIdx.x; l < 3072; l += 256) {
        int c = l / 96, s = l - c * 96;
        xsc[c * 100 + s] = x[(size_t)(b * 32 + c) * 4800 + n0 * 12 + s];
    }
    __syncthreads();
    int o = threadIdx.x & 63, slot = threadIdx.x >> 6;     // 4 slots
    for (int sg = slot; sg < 24; sg += 4) {
        float ad = bias[o];
        if (dsadd) ad += dsadd[(n0 + (4 * sg) / 12) * 64 + o];
        float c0 = ad, c1 = ad, c2 = ad, c3v = ad;
        for (int c = 0; c < 32; ++c) {
            float w = WT[(c << 6) + o];
            float4 xv = *(const float4*)(xsc + c * 100 + 4 * sg);
            c0 += xv.x * w; c1 += xv.y * w; c2 += xv.z * w; c3v += xv.w * w;
        }
        size_t ob = ((size_t)b * 4800 + n0 * 12 + 4 * sg) * 64 + o;
        out[ob] = c0;
        out[ob + 64] = c1;
        out[ob + 128] = c2;
        out[ob + 192] = c3v;
    }
}

// ---------------------------------------------------------------------------
// ds[n,e] = sum_m D_S[n,m] * W_embed[e,m] + b_embed[e]
// ---------------------------------------------------------------------------
__global__ void __launch_bounds__(64) k_ds(
    const float* __restrict__ D_S, const float* __restrict__ Wem,
    const float* __restrict__ bem, float* __restrict__ ds)
{
    __shared__ float row[400];
    int n = blockIdx.x;
    for (int i = threadIdx.x; i < 400; i += 64) row[i] = D_S[n * 400 + i];
    __syncthreads();
    int e = threadIdx.x;
    float acc = bem[e];
    const float* we = Wem + (size_t)e * 400;
    for (int m = 0; m < 400; ++m) acc += row[m] * we[m];
    ds[n * 64 + e] = acc;
}

// ---------------------------------------------------------------------------
// Ag partial (reference's mismatched reshape contraction)
// ---------------------------------------------------------------------------
__global__ void __launch_bounds__(256) k_agp(const float* __restrict__ xs,
                                             float* __restrict__ Ag)
{
    __shared__ float A[256 * 17], Bv[256 * 17];
    int i = blockIdx.x * 256 + threadIdx.x;  // < 6144
    int c1 = i / 192, b1 = (i / 12) & 15, t1 = i % 12;
    int t2 = i >> 9, b2 = (i >> 5) & 15, c2 = i & 31;
    for (int g = 0; g < 16; ++g) {
        A[threadIdx.x * 17 + g] = xs[((size_t)(b1 * 32 + c1) * 16 + g) * 12 + t1];
        Bv[threadIdx.x * 17 + g] = xs[((size_t)(b2 * 32 + c2) * 16 + g) * 12 + t2];
    }
    __syncthreads();
    int g1 = threadIdx.x >> 4, g2 = threadIdx.x & 15;
    float acc = 0.f;
    for (int k = 0; k < 256; ++k) acc += A[k * 17 + g1] * Bv[k * 17 + g2];
    atomicAdd(&Ag[threadIdx.x], acc);
}

// ---------------------------------------------------------------------------
// Ag -> relu(Ag-0.5) -> sg0/sg1 softmax(asym_adj)
// ---------------------------------------------------------------------------
__global__ void __launch_bounds__(64) k_agf(const float* __restrict__ Ag,
                                            float* __restrict__ sg0,
                                            float* __restrict__ sg1)
{
    __shared__ float Ar[256], rs[16], cs[16];
    int tid = threadIdx.x;
    for (int l = tid; l < 256; l += 64) Ar[l] = fmaxf(Ag[l] - 0.5f, 0.f);
    __syncthreads();
    if (tid < 16) {
        float r = 0.f, c = 0.f;
        for (int j = 0; j < 16; ++j) { r += Ar[tid * 16 + j]; c += Ar[j * 16 + tid]; }
        rs[tid] = (r > 0.f) ? 1.f / r : 0.f;
        cs[tid] = (c > 0.f) ? 1.f / c : 0.f;
    }
    __syncthreads();
    if (tid < 16) {
        float v[16], m, s;
        m = -1e30f;
        for (int j = 0; j < 16; ++j) { v[j] = Ar[tid * 16 + j] * rs[tid]; m = fmaxf(m, v[j]); }
        s = 0.f;
        for (int j = 0; j < 16; ++j) { v[j] = expf(v[j] - m); s += v[j]; }
        for (int j = 0; j < 16; ++j) sg0[tid * 16 + j] = v[j] / s;
        m = -1e30f;
        for (int j = 0; j < 16; ++j) { v[j] = Ar[j * 16 + tid] * cs[tid]; m = fmaxf(m, v[j]); }
        s = 0.f;
        for (int j = 0; j < 16; ++j) { v[j] = expf(v[j] - m); s += v[j]; }
        for (int j = 0; j < 16; ++j) sg1[tid * 16 + j] = v[j] / s;
    }
}

// ---------------------------------------------------------------------------
// QKV projection
// ---------------------------------------------------------------------------
__global__ void __launch_bounds__(256) k_qkv(
    const float* __restrict__ q, const float* __restrict__ Wq,
    const float* __restrict__ Wk, const float* __restrict__ Wv,
    float* __restrict__ qq, float* __restrict__ kk, float* __restrict__ vv)
{
    __shared__ float qs[64 * 33], wqT[1024], wkT[1024], wvT[1024];
    int g = blockIdx.x, n0 = blockIdx.y * 64;
    int b = g / 24, rem = g % 24, t = rem >> 1, h = rem & 1;
    int tid = threadIdx.x;
    for (int i = tid; i < 1024; i += 256) {
        int dd = i >> 5, e = i & 31;
        wqT[i] = Wq[e * 32 + dd];
        wkT[i] = Wk[e * 32 + dd];
        wvT[i] = Wv[e * 32 + dd];
    }
    for (int i = tid; i < 2048; i += 256) {
        int n = i >> 5, dd = i & 31;
        int gn = n0 + n;
        qs[n * 33 + dd] = (gn < 400)
            ? q[((size_t)b * 4800 + gn * 12 + t) * 64 + h * 32 + dd] : 0.f;
    }
    __syncthreads();
    int e = tid & 31, ng = tid >> 5;
    float aq[8], ak[8], av[8];
    #pragma unroll
    for (int k = 0; k < 8; ++k) { aq[k] = 0.f; ak[k] = 0.f; av[k] = 0.f; }
    for (int dd = 0; dd < 32; ++dd) {
        float wq = wqT[dd * 32 + e], wk = wkT[dd * 32 + e], wv = wvT[dd * 32 + e];
        #pragma unroll
        for (int k = 0; k < 8; ++k) {
            float xv = qs[(ng + 8 * k) * 33 + dd];
            aq[k] += xv * wq; ak[k] += xv * wk; av[k] += xv * wv;
        }
    }
    #pragma unroll
    for (int k = 0; k < 8; ++k) {
        int gn = n0 + ng + 8 * k;
        if (gn < 400) {
            size_t a = ((size_t)g * 400 + gn) * 32 + e;
            qq[a] = aq[k]; kk[a] = ak[k]; vv[a] = av[k];
        }
    }
}

// Softmax over one 7-slot energy row; writes p to PROW, sum into SVAR.
#define SMAX_ROW(EARR, PROW, SVAR) {                                          \
    if (l >= 16) EARR[6] = -1e30f;                                            \
    float m_ = EARR[0];                                                       \
    _Pragma("unroll") for (int j_ = 1; j_ < 7; ++j_) m_ = fmaxf(m_, EARR[j_]);\
    _Pragma("unroll") for (int o_ = 32; o_; o_ >>= 1)                         \
        m_ = fmaxf(m_, __shfl_xor(m_, o_));                                   \
    float ss_ = 0.f;                                                          \
    _Pragma("unroll") for (int j_ = 0; j_ < 7; ++j_) {                        \
        EARR[j_] = __expf((EARR[j_] - m_) * 0.125f); ss_ += EARR[j_]; }       \
    _Pragma("unroll") for (int o_ = 32; o_; o_ >>= 1)                         \
        ss_ += __shfl_xor(ss_, o_);                                           \
    SVAR = ss_;                                                               \
    _Pragma("unroll") for (int j_ = 0; j_ < 6; ++j_)                          \
        (PROW)[j_ * 64 + l] = EARR[j_];                                       \
    if (l < 16) (PROW)[384 + l] = EARR[6]; }

// ---------------------------------------------------------------------------
// Attention v5 = verified v3 structure (2 rows/wave, 52 VGPR, 273 us round 7)
// + single register-neutral tweak: V transposed [32][402] read as float2,
// halving V-read DS instructions in PV (2x b64 replace 4x b32; 2-way bank
// aliasing is free per m136). v4's 4-row variant hit the ~64-VGPR allocator
// cap at 1024 threads and spilled 5.4 GB/dispatch (round-8 profile) -- the
// working set MUST fit ~64 VGPRs at this block size.
// LDS: kkT 14368 + vvT 12864 + pbuf 12800 = 40032 fl = 160128 B.
// ---------------------------------------------------------------------------
__global__ void __launch_bounds__(1024, 4) k_attn5(
    const float* __restrict__ qq, const float* __restrict__ kk,
    const float* __restrict__ vv, float* __restrict__ attnO)
{
    extern __shared__ float lds[];
    float* kkT = lds;             // 32*449
    float* vvT = kkT + 14368;     // 32*402
    float* pbuf = vvT + 12864;    // 16 waves * 800

    int g = blockIdx.x >> 1, rh = blockIdx.x & 1;
    const float* qq_g = qq + (size_t)g * 12800;
    const float* kk_g = kk + (size_t)g * 12800;
    const float* vv_g = vv + (size_t)g * 12800;
    int tid = threadIdx.x;

    for (int i = tid; i < 1568; i += 1024) {         // zero pad keys 400..448
        int d = i / 49, c = i - d * 49;
        kkT[d * 449 + 400 + c] = 0.f;
    }
    for (int i = tid; i < 12800; i += 1024) {
        int k = i >> 5, d = i & 31;
        kkT[d * 449 + k] = kk_g[i];
        vvT[d * 402 + k] = vv_g[i];
    }
    __syncthreads();

    int w = tid >> 6, l = tid & 63;                  // w in 0..15
    float* pw = pbuf + w * 800;
    int b = g / 24, rem = g % 24, t = rem >> 1, h = rem & 1;
    size_t obase = ((size_t)b * 4800 + t) * 64 + h * 32;
    int hh = l >> 5, d = l & 31;
    int kb0 = hh * 200;

    for (int r0 = rh * 200 + w * 2; r0 < rh * 200 + 200; r0 += 32) {
        float e0[7], e1[7];
        #pragma unroll
        for (int j = 0; j < 7; ++j) { e0[j] = 0.f; e1[j] = 0.f; }

        for (int db = 0; db < 4; ++db) {
            float q0[8], q1[8];
            #pragma unroll
            for (int dd = 0; dd < 8; ++dd) {
                q0[dd] = qq_g[(r0 + 0) * 32 + db * 8 + dd];
                q1[dd] = qq_g[(r0 + 1) * 32 + db * 8 + dd];
            }
            #pragma unroll
            for (int j = 0; j < 7; ++j) {
                #pragma unroll
                for (int dd = 0; dd < 8; ++dd) {
                    float kv = kkT[(db * 8 + dd) * 449 + j * 64 + l];
                    e0[j] += q0[dd] * kv;
                    e1[j] += q1[dd] * kv;
                }
            }
        }
        float s0v, s1v;
        SMAX_ROW(e0, pw, s0v);
        SMAX_ROW(e1, pw + 400, s1v);
        asm volatile("" ::: "memory");   // wave-private LDS: in-order DS pipe

        float o0 = 0.f, o1 = 0.f;
        const float* pr0 = pw + kb0;
        const float* pr1 = pw + 400 + kb0;
        const float* vr = vvT + d * 402 + kb0;
        for (int kb = 0; kb < 200; kb += 4) {
            float4 p0 = *(const float4*)(pr0 + kb);
            float4 p1 = *(const float4*)(pr1 + kb);
            float2 va = *(const float2*)(vr + kb);
            float2 vb = *(const float2*)(vr + kb + 2);
            o0 += p0.x * va.x + p0.y * va.y + p0.z * vb.x + p0.w * vb.y;
            o1 += p1.x * va.x + p1.y * va.y + p1.z * vb.x + p1.w * vb.y;
        }
        asm volatile("" ::: "memory");
        o0 += __shfl_down(o0, 32);
        o1 += __shfl_down(o1, 32);
        if (l < 32) {
            attnO[obase + (size_t)(r0 + 0) * 768 + d] = o0 / s0v;
            attnO[obase + (size_t)(r0 + 1) * 768 + d] = o1 / s1v;
        }
    }
}

// ---------------------------------------------------------------------------
// A1 v2 (verified round 7): x = LN(attnO @ Wfc^T + bfc + q), 4x4 reg tile.
// ---------------------------------------------------------------------------
__global__ void __launch_bounds__(256) k_A1n(
    const float* __restrict__ attnO, const float* __restrict__ Wfc,
    const float* __restrict__ bfc, const float* __restrict__ qbuf,
    const float* __restrict__ w1, const float* __restrict__ b1,
    float* __restrict__ xout)
{
    __shared__ float WT[64 * 65], ao[64 * 65], qs[64 * 65];
    size_t R0 = (size_t)blockIdx.x * 64;
    int tid = threadIdx.x;
    for (int l = tid; l < 4096; l += 256) {
        int o = l >> 6, e = l & 63;
        WT[e * 65 + o] = Wfc[l];
    }
    for (int i = tid; i < 1024; i += 256) {
        int r = i >> 4, c4 = (i & 15) * 4;
        *(float4*)(ao + r * 65 + c4) = *(const float4*)(attnO + (R0 + r) * 64 + c4);
        *(float4*)(qs + r * 65 + c4) = *(const float4*)(qbuf + (R0 + r) * 64 + c4);
    }
    __syncthreads();

    int oj = tid & 15, ri = tid >> 4;
    float acc[4][4];
    #pragma unroll
    for (int rr = 0; rr < 4; ++rr)
        #pragma unroll
        for (int cc = 0; cc < 4; ++cc) acc[rr][cc] = 0.f;

    for (int eb = 0; eb < 16; ++eb) {
        float w[4][4], u[4][4];
        #pragma unroll
        for (int k = 0; k < 4; ++k) {
            float4 t = *(const float4*)(WT + (eb * 4 + k) * 65 + 4 * oj);
            w[k][0] = t.x; w[k][1] = t.y; w[k][2] = t.z; w[k][3] = t.w;
        }
        #pragma unroll
        for (int rr = 0; rr < 4; ++rr) {
            float4 t = *(const float4*)(ao + (4 * ri + rr) * 65 + eb * 4);
            u[rr][0] = t.x; u[rr][1] = t.y; u[rr][2] = t.z; u[rr][3] = t.w;
        }
        #pragma unroll
        for (int rr = 0; rr < 4; ++rr)
            #pragma unroll
            for (int k = 0; k < 4; ++k) {
                float uv = u[rr][k];
                acc[rr][0] += uv * w[k][0];
                acc[rr][1] += uv * w[k][1];
                acc[rr][2] += uv * w[k][2];
                acc[rr][3] += uv * w[k][3];
            }
    }
    float bf[4];
    #pragma unroll
    for (int cc = 0; cc < 4; ++cc) bf[cc] = bfc[4 * oj + cc];
    #pragma unroll
    for (int rr = 0; rr < 4; ++rr)
        #pragma unroll
        for (int cc = 0; cc < 4; ++cc) {
            int r = 4 * ri + rr, o = 4 * oj + cc;
            qs[r * 65 + o] += acc[rr][cc] + bf[cc];
        }
    __syncthreads();
    int r = tid >> 2, sb = tid & 3;
    float vals[16];
    float sm = 0.f;
    #pragma unroll
    for (int i = 0; i < 4; ++i) {
        float4 t = *(const float4*)(qs + r * 65 + sb * 16 + 4 * i);
        vals[4 * i + 0] = t.x; vals[4 * i + 1] = t.y;
        vals[4 * i + 2] = t.z; vals[4 * i + 3] = t.w;
        sm += t.x + t.y + t.z + t.w;
    }
    sm += __shfl_xor(sm, 1); sm += __shfl_xor(sm, 2);
    float mean = sm * (1.f / 64.f);
    float vs = 0.f;
    #pragma unroll
    for (int i = 0; i < 16; ++i) { float dv = vals[i] - mean; vs += dv * dv; }
    vs += __shfl_xor(vs, 1); vs += __shfl_xor(vs, 2);
    float inv = rsqrtf(vs * (1.f / 64.f) + 1e-5f);
    #pragma unroll
    for (int i = 0; i < 16; ++i) {
        int o = sb * 16 + i;
        xout[(R0 + r) * 64 + o] = (vals[i] - mean) * inv * w1[o] + b1[o];
    }
}

// ---------------------------------------------------------------------------
// A2 fused FF (unchanged)
// ---------------------------------------------------------------------------
__global__ void __launch_bounds__(512, 2) k_A2n(
    const float* __restrict__ xin, const float* __restrict__ Wff1,
    const float* __restrict__ bff1, const float* __restrict__ Wff2,
    const float* __restrict__ bff2, const float* __restrict__ w2,
    const float* __restrict__ b2, float* __restrict__ US)
{
    extern __shared__ float lds[];
    float* xs = lds;             // 64*65 = 4160
    float* Wb = xs + 4160;       // 16384
    float* fhT = Wb + 16384;     // 256*65 = 16640
    size_t R0 = (size_t)blockIdx.x * 64;
    int tid = threadIdx.x;
    for (int i = tid; i < 4096; i += 512) {
        int r = i >> 6, e = i & 63;
        xs[r * 65 + e] = xin[(R0 + r) * 64 + e];
    }
    for (int i = tid; i < 16384; i += 512) {
        int e = i >> 8, f = i & 255;
        Wb[i] = Wff1[f * 64 + e];
    }
    __syncthreads();
    int l = tid & 63, g = tid >> 6;
    {
        float acc[4][8];
        #pragma unroll
        for (int j = 0; j < 4; ++j)
            #pragma unroll
            for (int ri = 0; ri < 8; ++ri) acc[j][ri] = 0.f;
        for (int e = 0; e < 64; ++e) {
            float xr[8];
            #pragma unroll
            for (int ri = 0; ri < 8; ++ri) xr[ri] = xs[(g * 8 + ri) * 65 + e];
            #pragma unroll
            for (int j = 0; j < 4; ++j) {
                float wv = Wb[e * 256 + l + 64 * j];
                #pragma unroll
                for (int ri = 0; ri < 8; ++ri) acc[j][ri] += xr[ri] * wv;
            }
        }
        #pragma unroll
        for (int j = 0; j < 4; ++j) {
            float bb = bff1[l + 64 * j];
            #pragma unroll
            for (int ri = 0; ri < 8; ++ri)
                fhT[(l + 64 * j) * 65 + g * 8 + ri] = fmaxf(acc[j][ri] + bb, 0.f);
        }
    }
    __syncthreads();
    for (int i = tid; i < 16384; i += 512) {
        int f = i >> 6, o = i & 63;
        Wb[i] = Wff2[o * 256 + f];
    }
    __syncthreads();
    float acc2[8];
    #pragma unroll
    for (int oi = 0; oi < 8; ++oi) acc2[oi] = 0.f;
    for (int f = 0; f < 256; ++f) {
        float fv = fhT[f * 65 + l];
        float4 wa = *(const float4*)(Wb + f * 64 + g * 8);
        float4 wb_ = *(const float4*)(Wb + f * 64 + g * 8 + 4);
        acc2[0] += fv * wa.x;  acc2[1] += fv * wa.y;
        acc2[2] += fv * wa.z;  acc2[3] += fv * wa.w;
        acc2[4] += fv * wb_.x; acc2[5] += fv * wb_.y;
        acc2[6] += fv * wb_.z; acc2[7] += fv * wb_.w;
    }
    __syncthreads();
    float* lnb = Wb;
    float* mM = Wb + 4160;
    float* mI = Wb + 4224;
    #pragma unroll
    for (int oi = 0; oi < 8; ++oi) {
        int o = g * 8 + oi;
        lnb[l * 65 + o] = acc2[oi] + bff2[o] + xs[l * 65 + o];
    }
    __syncthreads();
    int r = tid >> 3, sb = tid & 7;
    float v[8];
    float sm = 0.f;
    #pragma unroll
    for (int i = 0; i < 8; ++i) { v[i] = lnb[r * 65 + sb + 8 * i]; sm += v[i]; }
    sm += __shfl_xor(sm, 1); sm += __shfl_xor(sm, 2); sm += __shfl_xor(sm, 4);
    float mean = sm * (1.f / 64.f);
    float vs = 0.f;
    #pragma unroll
    for (int i = 0; i < 8; ++i) { float dv = v[i] - mean; vs += dv * dv; }
    vs += __shfl_xor(vs, 1); vs += __shfl_xor(vs, 2); vs += __shfl_xor(vs, 4);
    float inv = rsqrtf(vs * (1.f / 64.f) + 1e-5f);
    if (sb == 0) { mM[r] = mean; mI[r] = inv; }
    __syncthreads();
    for (int i = tid; i < 4096; i += 512) {
        int rr = i >> 6, o = i & 63;
        US[(R0 + rr) * 64 + o] = (lnb[rr * 65 + o] - mM[rr]) * mI[rr] * w2[o] + b2[o];
    }
}

// ---------------------------------------------------------------------------
// A3 v2 (verified round 7): gate + blend + final conv, 4x4 reg tile.
// ---------------------------------------------------------------------------
__global__ void __launch_bounds__(256) k_A3n(
    const float* __restrict__ US, const float* __restrict__ Xc,
    const float* __restrict__ Wfs, const float* __restrict__ bfs,
    const float* __restrict__ Wfg, const float* __restrict__ bfg,
    const float* __restrict__ Wc11, const float* __restrict__ bc11,
    float* __restrict__ out)
{
    extern __shared__ float lds[];
    float* WsT = lds;
    float* WgT = WsT + 4160;
    float* WcT = WgT + 4160;
    float* us  = WcT + 2112;
    float* xc  = us + 4160;
    size_t R0 = (size_t)blockIdx.x * 64;
    int tid = threadIdx.x;
    for (int l = tid; l < 4096; l += 256) {
        int o = l >> 6, e = l & 63;
        WsT[e * 65 + o] = Wfs[l];
        WgT[e * 65 + o] = Wfg[l];
    }
    for (int l = tid; l < 2048; l += 256) {
        int oc = l >> 6, e = l & 63;
        WcT[e * 33 + oc] = Wc11[l];
    }
    for (int i = tid; i < 1024; i += 256) {
        int r = i >> 4, c4 = (i & 15) * 4;
        *(float4*)(us + r * 65 + c4) = *(const float4*)(US + (R0 + r) * 64 + c4);
        *(float4*)(xc + r * 65 + c4) = *(const float4*)(Xc + (R0 + r) * 64 + c4);
    }
    __syncthreads();

    int oj = tid & 15, ri = tid >> 4;
    float a1[4][4], a2[4][4];
    #pragma unroll
    for (int rr = 0; rr < 4; ++rr)
        #pragma unroll
        for (int cc = 0; cc < 4; ++cc) { a1[rr][cc] = 0.f; a2[rr][cc] = 0.f; }

    for (int eb = 0; eb < 16; ++eb) {
        {
            float w[4][4], u[4][4];
            #pragma unroll
            for (int k = 0; k < 4; ++k) {
                float4 t = *(const float4*)(WsT + (eb * 4 + k) * 65 + 4 * oj);
                w[k][0] = t.x; w[k][1] = t.y; w[k][2] = t.z; w[k][3] = t.w;
            }
            #pragma unroll
            for (int rr = 0; rr < 4; ++rr) {
                float4 t = *(const float4*)(us + (4 * ri + rr) * 65 + eb * 4);
                u[rr][0] = t.x; u[rr][1] = t.y; u[rr][2] = t.z; u[rr][3] = t.w;
            }
            #pragma unroll
            for (int rr = 0; rr < 4; ++rr)
                #pragma unroll
                for (int k = 0; k < 4; ++k) {
                    float uv = u[rr][k];
                    a1[rr][0] += uv * w[k][0];
                    a1[rr][1] += uv * w[k][1];
                    a1[rr][2] += uv * w[k][2];
                    a1[rr][3] += uv * w[k][3];
                }
        }
        {
            float w[4][4], u[4][4];
            #pragma unroll
            for (int k = 0; k < 4; ++k) {
                float4 t = *(const float4*)(WgT + (eb * 4 + k) * 65 + 4 * oj);
                w[k][0] = t.x; w[k][1] = t.y; w[k][2] = t.z; w[k][3] = t.w;
            }
            #pragma unroll
            for (int rr = 0; rr < 4; ++rr) {
                float4 t = *(const float4*)(xc + (4 * ri + rr) * 65 + eb * 4);
                u[rr][0] = t.x; u[rr][1] = t.y; u[rr][2] = t.z; u[rr][3] = t.w;
            }
            #pragma unroll
            for (int rr = 0; rr < 4; ++rr)
                #pragma unroll
                for (int k = 0; k < 4; ++k) {
                    float uv = u[rr][k];
                    a2[rr][0] += uv * w[k][0];
                    a2[rr][1] += uv * w[k][1];
                    a2[rr][2] += uv * w[k][2];
                    a2[rr][3] += uv * w[k][3];
                }
        }
    }
    __syncthreads();
    float bs[4], bg2[4];
    #pragma unroll
    for (int cc = 0; cc < 4; ++cc) { bs[cc] = bfs[4 * oj + cc]; bg2[cc] = bfg[4 * oj + cc]; }
    #pragma unroll
    for (int rr = 0; rr < 4; ++rr)
        #pragma unroll
        for (int cc = 0; cc < 4; ++cc) {
            int r = 4 * ri + rr, o = 4 * oj + cc;
            float gg = 1.f / (1.f + __expf(-(a1[rr][cc] + bs[cc] + a2[rr][cc] + bg2[cc])));
            float uv = us[r * 65 + o], xv = xc[r * 65 + o];
            us[r * 65 + o] = gg * uv + (1.f - gg) * xv;
        }
    __syncthreads();

    int ocj = tid & 7, rg = tid >> 3;
    float c2[2][4];
    #pragma unroll
    for (int rr = 0; rr < 2; ++rr)
        #pragma unroll
        for (int cc = 0; cc < 4; ++cc) c2[rr][cc] = bc11[4 * ocj + cc];
    for (int eb = 0; eb < 16; ++eb) {
        float w[4][4], p[2][4];
        #pragma unroll
        for (int k = 0; k < 4; ++k) {
            float4 t = *(const float4*)(WcT + (eb * 4 + k) * 33 + 4 * ocj);
            w[k][0] = t.x; w[k][1] = t.y; w[k][2] = t.z; w[k][3] = t.w;
        }
        #pragma unroll
        for (int rr = 0; rr < 2; ++rr) {
            float4 t = *(const float4*)(us + (2 * rg + rr) * 65 + eb * 4);
            p[rr][0] = t.x; p[rr][1] = t.y; p[rr][2] = t.z; p[rr][3] = t.w;
        }
        #pragma unroll
        for (int rr = 0; rr < 2; ++rr)
            #pragma unroll
            for (int k = 0; k < 4; ++k) {
                float pv = p[rr][k];
                c2[rr][0] += pv * w[k][0];
                c2[rr][1] += pv * w[k][1];
                c2[rr][2] += pv * w[k][2];
                c2[rr][3] += pv * w[k][3];
            }
    }
    int b = (int)(R0 / 4800);
    int rr0 = (int)(R0 % 4800);
    #pragma unroll
    for (int cc = 0; cc < 4; ++cc)
        #pragma unroll
        for (int rr = 0; rr < 2; ++rr)
            out[(size_t)(b * 32 + 4 * ocj + cc) * 4800 + rr0 + 2 * rg + rr] = c2[rr][cc];
}

// ---------------------------------------------------------------------------
extern "C" void kernel_launch(void* const* d_in, const int* in_sizes, int n_in,
                              void* d_out, int out_size, void* d_ws, size_t ws_size,
                              hipStream_t stream)
{
    (void)in_sizes; (void)n_in; (void)out_size; (void)ws_size;
    const float* query = (const float*)d_in[2];
    const float* s0    = (const float*)d_in[3];
    const float* s1    = (const float*)d_in[4];
    const float* sr0   = (const float*)d_in[5];
    const float* sr1   = (const float*)d_in[6];
    const float* Mrg   = (const float*)d_in[7];
    const float* Mor   = (const float*)d_in[8];
    const float* D_S   = (const float*)d_in[9];
    const float* Wc1   = (const float*)d_in[10];
    const float* bc1   = (const float*)d_in[11];
    const float* Wc11  = (const float*)d_in[12];
    const float* bc11  = (const float*)d_in[13];
    const float* Wg    = (const float*)d_in[14];
    const float* bg    = (const float*)d_in[15];
    const float* Wem   = (const float*)d_in[16];
    const float* bem   = (const float*)d_in[17];
    const float* Wq    = (const float*)d_in[18];
    const float* Wk    = (const float*)d_in[19];
    const float* Wv    = (const float*)d_in[20];
    const float* Wfc   = (const float*)d_in[21];
    const float* bfc   = (const float*)d_in[22];
    const float* ln1w  = (const float*)d_in[23];
    const float* ln1b  = (const float*)d_in[24];
    const float* ln2w  = (const float*)d_in[25];
    const float* ln2b  = (const float*)d_in[26];
    const float* Wff1  = (const float*)d_in[27];
    const float* bff1  = (const float*)d_in[28];
    const float* Wff2  = (const float*)d_in[29];
    const float* bff2  = (const float*)d_in[30];
    const float* Wfs   = (const float*)d_in[31];
    const float* bfs   = (const float*)d_in[32];
    const float* Wfg   = (const float*)d_in[33];
    const float* bfg   = (const float*)d_in[34];

    float* ws = (float*)d_ws;
    size_t off = 0;
    auto alloc = [&](size_t n) { float* p = ws + off; off += n; return p; };
    float* q_buf = alloc(4915200);   // (B,N,T,E)
    float* Xc    = alloc(4915200);   // doubles as qq pre-CHGCN
    float* x_buf = alloc(4915200);   // doubles as attnO (in-place A1)
    float* US    = alloc(4915200);   // doubles as vv pre-A2
    float* ho    = alloc(2457600);   // (B,C,N,T)
    float* t0    = alloc(2457600);
    float* t1    = alloc(2457600);   // t0+t1 contiguous: doubles as kk
    float* xr    = alloc(393216);    // (B,C,R,T)
    float* tr0   = alloc(393216);
    float* tr1   = alloc(393216);
    float* hr    = alloc(393216);
    float* xsg   = alloc(98304);     // (B,C,G,T)
    float* tg0   = alloc(98304);
    float* tg1   = alloc(98304);
    float* xg0   = alloc(98304);
    float* dsb   = alloc(25600);     // (N,E)
    float* Ag    = alloc(256);
    float* sg0   = alloc(256);
    float* sg1   = alloc(256);

    float* qq    = Xc;               // live only during [k_qkv, k_attn5]
    float* kk    = t0;
    float* vv    = US;
    float* attnO = x_buf;

    float* out_main = (float*)d_out;          // (B,C,N,T)
    float* out_xc   = out_main + 2457600;     // (B,C,R,T) final hr
    float* out_xs   = out_main + 2850816;     // (B,C,G,T) final xg

    hipFuncSetAttribute((const void*)k_attn5,
                        hipFuncAttributeMaxDynamicSharedMemorySize, 160128);
    hipFuncSetAttribute((const void*)k_A2n,
                        hipFuncAttributeMaxDynamicSharedMemorySize, 148736);
    hipFuncSetAttribute((const void*)k_A3n,
                        hipFuncAttributeMaxDynamicSharedMemorySize, 75008);

    hipMemsetAsync(Ag, 0, 256 * sizeof(float), stream);

    // ---- Transformer front ----
    k_ds<<<400, 64, 0, stream>>>(D_S, Wem, bem, dsb);
    k_conv1<<<800, 256, 0, stream>>>(query, Wc1, bc1, dsb, q_buf);
    k_qkv<<<dim3(384, 7), 256, 0, stream>>>(q_buf, Wq, Wk, Wv, qq, kk, vv);
    k_attn5<<<768, 1024, 160128, stream>>>(qq, kk, vv, attnO);
    k_A1n<<<1200, 256, 0, stream>>>(attnO, Wfc, bfc, q_buf, ln1w, ln1b, x_buf);
    k_A2n<<<1200, 512, 148736, stream>>>(x_buf, Wff1, bff1, Wff2, bff2,
                                         ln2w, ln2b, US);

    // ---- CHGCN ----
    k_spatial<<<dim3(512, 4), 256, 0, stream>>>(s0, 1, 400, 400, query, nullptr, 1.f, 0, t0);
    k_spatial<<<dim3(512, 4), 256, 0, stream>>>(s1, 1, 400, 400, query, nullptr, 1.f, 0, t1);
    k_gcn_combine<<<800, 256, 0, stream>>>(query, t0, t1, Wg, bg, 400, ho);
    k_spatial<<<dim3(512, 1), 256, 0, stream>>>(Mor, 1, 400, 64, query, nullptr, 1.f, 0, xr);
    k_spatial<<<dim3(512, 1), 256, 0, stream>>>(sr0, 1, 64, 64, xr, nullptr, 1.f, 0, tr0);
    k_spatial<<<dim3(512, 1), 256, 0, stream>>>(sr1, 1, 64, 64, xr, nullptr, 1.f, 0, tr1);
    k_gcn_combine<<<128, 256, 0, stream>>>(xr, tr0, tr1, Wg, bg, 64, hr);
    k_spatial<<<dim3(512, 1), 256, 0, stream>>>(Mrg, 1, 64, 16, xr, nullptr, 1.f, 0, xsg);
    k_agp<<<24, 256, 0, stream>>>(xsg, Ag);
    k_agf<<<1, 64, 0, stream>>>(Ag, sg0, sg1);
    k_spatial<<<dim3(512, 1), 256, 0, stream>>>(sg0, 1, 16, 16, xsg, nullptr, 1.f, 0, tg0);
    k_spatial<<<dim3(512, 1), 256, 0, stream>>>(sg1, 1, 16, 16, xsg, nullptr, 1.f, 0, tg1);
    k_gcn_combine<<<32, 256, 0, stream>>>(xsg, tg0, tg1, Wg, bg, 16, xg0);
    k_spatial<<<dim3(512, 1), 256, 0, stream>>>(Mrg, 0, 16, 64, xg0, hr, 0.5f, 1, hr);
    k_spatial<<<dim3(512, 4), 256, 0, stream>>>(Mor, 0, 64, 400, hr, ho, 0.5f, 1, ho);
    k_spatial<<<dim3(512, 1), 256, 0, stream>>>(Mor, 1, 400, 64, ho, hr, 0.5f, 1, out_xc);
    k_spatial<<<dim3(512, 1), 256, 0, stream>>>(Mrg, 1, 64, 16, out_xc, xg0, 0.5f, 1, out_xs);

    // ---- Tail ----
    k_conv1<<<800, 256, 0, stream>>>(ho, Wc1, bc1, nullptr, Xc);
    k_A3n<<<1200, 256, 75008, stream>>>(US, Xc, Wfs, bfs, Wfg, bfg, Wc11, bc11, out_main);
}